// Round 5
// baseline (599.154 us; speedup 1.0000x reference)
//
#include <hip/hip_runtime.h>

#define DEV __device__ __forceinline__

constexpr int FDIM = 128;
constexpr float LRELU_S = 0.2f;

typedef _Float16 half_t;
typedef _Float16 f16x2 __attribute__((ext_vector_type(2)));
typedef _Float16 f16x4 __attribute__((ext_vector_type(4)));
typedef _Float16 f16x8 __attribute__((ext_vector_type(8)));
typedef float    f32x4 __attribute__((ext_vector_type(4)));

DEV float wsum64(float v){
#pragma unroll
  for (int off = 32; off > 0; off >>= 1) v += __shfl_xor(v, off, 64);
  return v;
}
DEV float lrelu(float x){ return x >= 0.f ? x : LRELU_S * x; }

// ================= k_prep: transpose W0/1/2 -> fp16 [n][k], zero bcnt ========
__global__ __launch_bounds__(256)
void k_prep(const float* __restrict__ W0, const float* __restrict__ W1,
            const float* __restrict__ W2, half_t* __restrict__ Wt,
            int* __restrict__ bcnt, int nb){
  int b = blockIdx.x, t = threadIdx.x;
  if (b < 48){
    int which = b >> 4, rep = b & 15;
    const float* W = which == 0 ? W0 : (which == 1 ? W1 : W2);
    int e = rep * 1024 + t * 4;
    int k = e >> 7, n0 = e & 127;
    float4 wv = *(const float4*)(W + e);
    half_t* dst = Wt + which * 16384;
    dst[(n0 + 0) * 128 + k] = (half_t)wv.x;
    dst[(n0 + 1) * 128 + k] = (half_t)wv.y;
    dst[(n0 + 2) * 128 + k] = (half_t)wv.z;
    dst[(n0 + 3) * 128 + k] = (half_t)wv.w;
  } else {
    int i = (b - 48) * 256 + t;
    if (i < nb) bcnt[i] = 0;
  }
}

// ================= CSR build: LDS-bucketed counting sort =================
__global__ __launch_bounds__(256)
void k_bp1(const int* __restrict__ dst, int* __restrict__ bcnt, int e, int chunk){
  __shared__ int hist[1024];
  int t = threadIdx.x;
  int lo = blockIdx.x * chunk, hi = min(e, lo + chunk);
  for (int i = t; i < 1024; i += 256) hist[i] = 0;
  __syncthreads();
  for (int j = lo + t; j < hi; j += 256) atomicAdd(&hist[dst[j] >> 7], 1);
  __syncthreads();
  for (int i = t; i < 1024; i += 256){
    int c = hist[i];
    if (c) atomicAdd(&bcnt[i], c);
  }
}

__global__ __launch_bounds__(256)
void k_bscan(const int* __restrict__ bcnt, int* __restrict__ boff,
             int* __restrict__ bcur, int nb, int e){
  __shared__ int sd[256];
  int t = threadIdx.x;
  int i0 = t * 4;
  int v[4]; int tot = 0;
#pragma unroll
  for (int j = 0; j < 4; ++j){
    v[j] = (i0 + j < nb) ? bcnt[i0 + j] : 0;
    tot += v[j];
  }
  sd[t] = tot;
  __syncthreads();
  for (int off = 1; off < 256; off <<= 1){
    int o = (t >= off) ? sd[t - off] : 0;
    __syncthreads();
    sd[t] += o;
    __syncthreads();
  }
  int run = sd[t] - tot;
#pragma unroll
  for (int j = 0; j < 4; ++j){
    if (i0 + j < nb){ boff[i0 + j] = run; bcur[i0 + j] = run; }
    run += v[j];
  }
  if (t == 0) boff[nb] = e;
}

__global__ __launch_bounds__(256)
void k_bp2(const int* __restrict__ src, const int* __restrict__ dst,
           int* __restrict__ bcur, int2* __restrict__ ebuf, int e, int chunk){
  __shared__ int hist[1024];
  __shared__ int base[1024];
  int t = threadIdx.x;
  int lo = blockIdx.x * chunk, hi = min(e, lo + chunk);
  for (int i = t; i < 1024; i += 256) hist[i] = 0;
  __syncthreads();
  for (int j = lo + t; j < hi; j += 256) atomicAdd(&hist[dst[j] >> 7], 1);
  __syncthreads();
  for (int i = t; i < 1024; i += 256){
    int c = hist[i];
    base[i] = c ? atomicAdd(&bcur[i], c) : 0;
    hist[i] = 0;
  }
  __syncthreads();
  for (int j = lo + t; j < hi; j += 256){
    int d = dst[j];
    int b = d >> 7;
    int r = atomicAdd(&hist[b], 1);
    ebuf[base[b] + r] = make_int2(src[j], d);
  }
}

__global__ __launch_bounds__(256)
void k_bdeg(const int2* __restrict__ ebuf, const int* __restrict__ boff,
            int* __restrict__ deg, int n){
  __shared__ int cnt[128];
  int b = blockIdx.x, t = threadIdx.x;
  if (t < 128) cnt[t] = 1;   // self-loop
  __syncthreads();
  int lo = boff[b], hi = boff[b + 1];
  for (int j = lo + t; j < hi; j += 256) atomicAdd(&cnt[ebuf[j].y & 127], 1);
  __syncthreads();
  int node = b * 128 + t;
  if (t < 128 && node < n) deg[node] = cnt[t];
}

__global__ void k_scan1(const int* __restrict__ deg, int* __restrict__ rp,
                        int* __restrict__ csum, int n){
  __shared__ int sd[256];
  int t = threadIdx.x, b = blockIdx.x;
  int base = b * 1024 + t * 4;
  int v0 = (base     < n) ? deg[base]     : 0;
  int v1 = (base + 1 < n) ? deg[base + 1] : 0;
  int v2 = (base + 2 < n) ? deg[base + 2] : 0;
  int v3 = (base + 3 < n) ? deg[base + 3] : 0;
  int tot = v0 + v1 + v2 + v3;
  sd[t] = tot;
  __syncthreads();
  for (int off = 1; off < 256; off <<= 1){
    int o = (t >= off) ? sd[t - off] : 0;
    __syncthreads();
    sd[t] += o;
    __syncthreads();
  }
  int excl = sd[t] - tot;
  if (base     < n) rp[base]     = excl;
  if (base + 1 < n) rp[base + 1] = excl + v0;
  if (base + 2 < n) rp[base + 2] = excl + v0 + v1;
  if (base + 3 < n) rp[base + 3] = excl + v0 + v1 + v2;
  if (t == 255) csum[b] = sd[255];
}
__global__ void k_scan2(int* __restrict__ csum, int nch){
  __shared__ int sd[128];
  int t = threadIdx.x;
  int my = (t < nch) ? csum[t] : 0;
  sd[t] = my;
  __syncthreads();
  for (int off = 1; off < 128; off <<= 1){
    int o = (t >= off) ? sd[t - off] : 0;
    __syncthreads();
    sd[t] += o;
    __syncthreads();
  }
  if (t < nch) sd[t] = sd[t] - my;
  if (t < nch) csum[t] = sd[t];
}

// fill col; also finalizes rp (adds csum chunk offsets) so scan3 is fused here.
__global__ __launch_bounds__(256)
void k_bfill(const int2* __restrict__ ebuf, const int* __restrict__ boff,
             int* __restrict__ rp, const int* __restrict__ csum,
             int* __restrict__ col, int n, int tot){
  __shared__ int cur2[128];
  int b = blockIdx.x, t = threadIdx.x;
  int node = b * 128 + t;
  if (t < 128 && node < n){
    int r0 = rp[node] + csum[node >> 10];
    rp[node] = r0;
    col[r0] = node;          // self-loop first
    cur2[t] = r0 + 1;
  }
  if (b == 0 && t == 0) rp[n] = tot;
  __syncthreads();
  int lo = boff[b], hi = boff[b + 1];
  for (int j = lo + t; j < hi; j += 256){
    int2 ed = ebuf[j];
    int pos = atomicAdd(&cur2[ed.y & 127], 1);
    col[pos] = ed.x;
  }
}

// ====== MFMA GEMM: feat[M,128](fp16) = A[M,128](fp32) @ Wt16[n][k](fp16)
// ====== + fused attention scores asb/adb
template<int HEADS>
__global__ __launch_bounds__(256)
void gemm_mfma(const float* __restrict__ A, const half_t* __restrict__ Wt16,
               const float* __restrict__ att_s, const float* __restrict__ att_d,
               half_t* __restrict__ feat, float* __restrict__ asb,
               float* __restrict__ adb, int M){
  __shared__ __align__(16) unsigned char lds[53248];
  half_t* Ah = (half_t*)lds;              // [128][72] halfs, K-chunk of 64
  half_t* Wt = (half_t*)(lds + 18432);    // [n=128][k=128] stride 136
  float*  tr = (float*)lds;               // epilogue: [4][32][68] f32

  int tid = threadIdx.x;
  int row0 = blockIdx.x * 128;
  int wid = tid >> 6, l = tid & 63;
  int wr = wid >> 1, wc = wid & 1;
  int lr = l & 15, lk = (l >> 4) * 8;

  // stage pre-transposed W: coalesced copy, 8 x 16B per thread
  {
    const f16x8* gW = (const f16x8*)Wt16;
#pragma unroll
    for (int rep = 0; rep < 8; ++rep){
      int c = rep * 256 + tid;            // 16B chunk id (2048 total)
      *(f16x8*)&Wt[(c >> 4) * 136 + (c & 15) * 8] = gW[c];
    }
  }

  f32x4 acc[4][4];
#pragma unroll
  for (int mt = 0; mt < 4; ++mt)
#pragma unroll
    for (int nt = 0; nt < 4; ++nt)
      acc[mt][nt] = (f32x4){0.f, 0.f, 0.f, 0.f};

  for (int kc = 0; kc < 2; ++kc){
    __syncthreads();
    for (int rep = 0; rep < 8; ++rep){
      int e = rep * 1024 + tid * 4;
      int r = e >> 6, c = e & 63;
      int gr = row0 + r;
      float4 av = make_float4(0.f, 0.f, 0.f, 0.f);
      if (gr < M) av = *(const float4*)(A + (long long)gr * FDIM + kc * 64 + c);
      f16x4 h4 = {(half_t)av.x, (half_t)av.y, (half_t)av.z, (half_t)av.w};
      *(f16x4*)&Ah[r * 72 + c] = h4;
    }
    __syncthreads();
#pragma unroll
    for (int ksl = 0; ksl < 2; ++ksl){
      f16x8 af[4], bf[4];
      int klds = ksl * 32 + lk;
      int kw   = kc * 64 + ksl * 32 + lk;
#pragma unroll
      for (int mt = 0; mt < 4; ++mt)
        af[mt] = *(const f16x8*)&Ah[(wr * 64 + mt * 16 + lr) * 72 + klds];
#pragma unroll
      for (int nt = 0; nt < 4; ++nt)
        bf[nt] = *(const f16x8*)&Wt[(wc * 64 + nt * 16 + lr) * 136 + kw];
#pragma unroll
      for (int mt = 0; mt < 4; ++mt)
#pragma unroll
        for (int nt = 0; nt < 4; ++nt)
          acc[mt][nt] = __builtin_amdgcn_mfma_f32_16x16x32_f16(af[mt], bf[nt],
                                                               acc[mt][nt], 0, 0, 0);
    }
  }

  const int q  = tid & 3;
  const int ri = tid >> 2;
  for (int p = 0; p < 2; ++p){
    __syncthreads();
#pragma unroll
    for (int mtl = 0; mtl < 2; ++mtl){
      int mt = p * 2 + mtl;
#pragma unroll
      for (int j = 0; j < 4; ++j){
        int rowl = mtl * 16 + (l >> 4) * 4 + j;
        float* dstp = tr + (wid * 32 + rowl) * 68 + lr;
#pragma unroll
        for (int nt = 0; nt < 4; ++nt)
          dstp[nt * 16] = acc[mt][nt][j];
      }
    }
    __syncthreads();
    int br = (ri >> 5) * 64 + p * 32 + (ri & 31);
    int gr = row0 + br;
    const float* srcp = tr + (((ri >> 5) * 2 + (q >> 1)) * 32 + (ri & 31)) * 68
                          + (q & 1) * 32;
    float vals[32];
#pragma unroll
    for (int u = 0; u < 8; ++u){
      float4 v = *(const float4*)&srcp[u * 4];
      vals[u*4+0] = v.x; vals[u*4+1] = v.y; vals[u*4+2] = v.z; vals[u*4+3] = v.w;
    }
    float sc_s = 0.f, sc_d = 0.f;
#pragma unroll
    for (int cc = 0; cc < 32; ++cc){
      sc_s = fmaf(vals[cc], att_s[q * 32 + cc], sc_s);
      sc_d = fmaf(vals[cc], att_d[q * 32 + cc], sc_d);
    }
    if (HEADS == 4){
      if (gr < M){ asb[gr * 4 + q] = sc_s; adb[gr * 4 + q] = sc_d; }
    } else {
      sc_s += __shfl_xor(sc_s, 1, 64); sc_s += __shfl_xor(sc_s, 2, 64);
      sc_d += __shfl_xor(sc_d, 1, 64); sc_d += __shfl_xor(sc_d, 2, 64);
      if (q == 0 && gr < M){ asb[gr] = sc_s; adb[gr] = sc_d; }
    }
    if (gr < M){
#pragma unroll
      for (int u = 0; u < 4; ++u){
        f16x8 h8 = {(half_t)vals[u*8+0], (half_t)vals[u*8+1], (half_t)vals[u*8+2],
                    (half_t)vals[u*8+3], (half_t)vals[u*8+4], (half_t)vals[u*8+5],
                    (half_t)vals[u*8+6], (half_t)vals[u*8+7]};
        *(f16x8*)&feat[(long long)gr * FDIM + q * 32 + u * 8] = h8;
      }
    }
  }
}

// ------- aggregation + epilogue: one wave per dst node, 2 edges/iter -------
// lanes 0-31 even edges, 32-63 odd edges; each lane covers 4 channels.
template<int HEADS, int MODE>
__global__ __launch_bounds__(256)
void k_agg(const half_t* __restrict__ feat, const float* __restrict__ asb,
           const float* __restrict__ adb, const int* __restrict__ rp,
           const int* __restrict__ col, const float* __restrict__ bias,
           const float* __restrict__ gamma, const float* __restrict__ beta,
           const float* __restrict__ prw, const float* __restrict__ resid,
           float* __restrict__ out, int n){
  __shared__ float wbuf[4][64 * HEADS];
  __shared__ int   sbuf[4][64];
  int wid = threadIdx.x >> 6;
  int i = (blockIdx.x * 256 + threadIdx.x) >> 6;
  if (i >= n) return;
  int l = threadIdx.x & 63;
  int s = rp[i], epos = rp[i + 1];
  int lh = l & 31;            // channel-group lane
  int c0 = lh * 4;            // 4 channels per lane
  int hh = lh >> 3;           // head of my channel group (HEADS==4)
  int hf = l >> 5;            // 0: even edges, 1: odd edges

  float ad0, ad1 = 0.f, ad2 = 0.f, ad3 = 0.f;
  if (HEADS == 4){
    float4 adv = *(const float4*)&adb[i * 4];
    ad0 = adv.x; ad1 = adv.y; ad2 = adv.z; ad3 = adv.w;
  } else {
    ad0 = adb[i];
  }

  float den0 = 0.f, den1 = 0.f, den2 = 0.f, den3 = 0.f;
  float a0 = 0.f, a1 = 0.f, a2 = 0.f, a3 = 0.f;
  for (int base = s; base < epos; base += 64){
    int j = base + l;
    int offb = 0;
    float w0 = 0.f, w1 = 0.f, w2 = 0.f, w3 = 0.f;
    if (j < epos){
      int sj = col[j];
      offb = sj << 8;        // byte offset of fp16 feat row (128*2B)
      if (HEADS == 4){
        float4 a4 = *(const float4*)&asb[sj * 4];
        w0 = __expf(lrelu(a4.x + ad0)); den0 += w0;
        w1 = __expf(lrelu(a4.y + ad1)); den1 += w1;
        w2 = __expf(lrelu(a4.z + ad2)); den2 += w2;
        w3 = __expf(lrelu(a4.w + ad3)); den3 += w3;
      } else {
        w0 = __expf(lrelu(asb[sj] + ad0)); den0 += w0;
      }
    }
    sbuf[wid][l] = offb;
    if (HEADS == 4)
      *(float4*)&wbuf[wid][l * 4] = make_float4(w0, w1, w2, w3);
    else
      wbuf[wid][l] = w0;
    __builtin_amdgcn_wave_barrier();
    int cnt = epos - base; if (cnt > 64) cnt = 64;
    int iters = (cnt + 1) >> 1;
    const char* fb = (const char*)feat;
#pragma unroll 8
    for (int t = 0; t < iters; ++t){
      int e = 2 * t + hf;
      int off = sbuf[wid][e] + c0 * 2;
      float w = (HEADS == 4) ? wbuf[wid][e * 4 + hh] : wbuf[wid][e];
      f16x4 f = *(const f16x4*)(fb + off);
      a0 = fmaf(w, (float)f[0], a0);
      a1 = fmaf(w, (float)f[1], a1);
      a2 = fmaf(w, (float)f[2], a2);
      a3 = fmaf(w, (float)f[3], a3);
    }
    __builtin_amdgcn_wave_barrier();
  }
  den0 = wsum64(den0);
  if (HEADS == 4){ den1 = wsum64(den1); den2 = wsum64(den2); den3 = wsum64(den3); }
  float dh = (HEADS == 1) ? den0
           : (hh < 2 ? (hh == 0 ? den0 : den1) : (hh == 2 ? den2 : den3));

  // fold even/odd halves (lanes l and l^32 then hold identical values)
  a0 += __shfl_xor(a0, 32, 64);
  a1 += __shfl_xor(a1, 32, 64);
  a2 += __shfl_xor(a2, 32, 64);
  a3 += __shfl_xor(a3, 32, 64);

  float inv = 1.f / (dh + 1e-16f);
  float4 bi = *(const float4*)&bias[c0];
  float r0 = fmaf(a0, inv, bi.x);
  float r1 = fmaf(a1, inv, bi.y);
  float r2 = fmaf(a2, inv, bi.z);
  float r3 = fmaf(a3, inv, bi.w);
  float4 rs = *(const float4*)&resid[(long long)i * FDIM + c0];
  float4 o;
  if (MODE == 0){
    // halves duplicated -> sums count each channel twice -> /256
    float mean = wsum64(r0 + r1 + r2 + r3) * (1.f / 256.f);
    float d0 = r0 - mean, d1 = r1 - mean, d2 = r2 - mean, d3 = r3 - mean;
    float var = wsum64(d0*d0 + d1*d1 + d2*d2 + d3*d3) * (1.f / 256.f);
    float rstd = rsqrtf(var + 1e-5f);
    float pw = prw[0];
    float4 gm = *(const float4*)&gamma[c0];
    float4 bt = *(const float4*)&beta[c0];
    float y0 = d0 * rstd * gm.x + bt.x;
    float y1 = d1 * rstd * gm.y + bt.y;
    float y2 = d2 * rstd * gm.z + bt.z;
    float y3 = d3 * rstd * gm.w + bt.w;
    y0 = (y0 >= 0.f) ? y0 : pw * y0;
    y1 = (y1 >= 0.f) ? y1 : pw * y1;
    y2 = (y2 >= 0.f) ? y2 : pw * y2;
    y3 = (y3 >= 0.f) ? y3 : pw * y3;
    o = make_float4(y0 + rs.x, y1 + rs.y, y2 + rs.z, y3 + rs.w);
  } else {
    o = make_float4(r0 + rs.x, r1 + rs.y, r2 + rs.z, r3 + rs.w);
  }
  if (l < 32)
    *(float4*)&out[(long long)i * FDIM + c0] = o;
}

// ---------------- launch ----------------
static inline int cdiv(int a, int b){ return (a + b - 1) / b; }

extern "C" void kernel_launch(void* const* d_in, const int* in_sizes, int n_in,
                              void* d_out, int out_size, void* d_ws, size_t ws_size,
                              hipStream_t stream){
  const float* x     = (const float*)d_in[0];
  const int*   eidx  = (const int*)d_in[1];
  const float* W0    = (const float*)d_in[2];
  const float* asr0  = (const float*)d_in[3];
  const float* adt0  = (const float*)d_in[4];
  const float* b0    = (const float*)d_in[5];
  const float* g0    = (const float*)d_in[6];
  const float* be0   = (const float*)d_in[7];
  const float* p0    = (const float*)d_in[8];
  const float* W1    = (const float*)d_in[9];
  const float* asr1  = (const float*)d_in[10];
  const float* adt1  = (const float*)d_in[11];
  const float* b1    = (const float*)d_in[12];
  const float* g1    = (const float*)d_in[13];
  const float* be1   = (const float*)d_in[14];
  const float* p1    = (const float*)d_in[15];
  const float* W2    = (const float*)d_in[16];
  const float* asr2  = (const float*)d_in[17];
  const float* adt2  = (const float*)d_in[18];
  const float* b2    = (const float*)d_in[19];

  const int N = in_sizes[0] / FDIM;     // 100000
  const int E = in_sizes[1] / 2;        // 1600000
  const int TOT = E + N;
  const int NB = (N + 127) >> 7;        // buckets of 128 nodes (<=1024)

  char* p = (char*)d_ws;
  auto alloc = [&](size_t bytes) -> void* {
    void* r = (void*)p;
    p += (bytes + 255) & ~(size_t)255;
    return r;
  };
  int*    deg  = (int*)   alloc((size_t)N * 4);
  int*    rp   = (int*)   alloc((size_t)(N + 1) * 4);
  int*    csum = (int*)   alloc(128 * 4);
  int*    bcnt = (int*)   alloc(1024 * 4);
  int*    boff = (int*)   alloc(1025 * 4);
  int*    bcur = (int*)   alloc(1024 * 4);
  int2*   ebuf = (int2*)  alloc((size_t)E * 8);
  int*    col  = (int*)   alloc((size_t)TOT * 4);
  half_t* feat = (half_t*)alloc((size_t)N * FDIM * 2);
  half_t* Wt16 = (half_t*)alloc(3 * 16384 * 2);
  float*  asb  = (float*) alloc((size_t)N * 4 * 4);
  float*  adb  = (float*) alloc((size_t)N * 4 * 4);
  float*  hA   = (float*) alloc((size_t)N * FDIM * 4);
  float*  hB   = (float*) alloc((size_t)N * FDIM * 4);
  (void)ws_size; (void)n_in; (void)out_size;

  const int nch = cdiv(N, 1024);
  const int SBLK = 256;
  const int chunk = cdiv(E, SBLK);

  // ---- prep (W transpose + bcnt zero) and CSR build ----
  k_prep<<<48 + cdiv(NB, 256), 256, 0, stream>>>(W0, W1, W2, Wt16, bcnt, NB);
  k_bp1<<<SBLK, 256, 0, stream>>>(eidx + E, bcnt, E, chunk);
  k_bscan<<<1, 256, 0, stream>>>(bcnt, boff, bcur, NB, E);
  k_bp2<<<SBLK, 256, 0, stream>>>(eidx, eidx + E, bcur, ebuf, E, chunk);
  k_bdeg<<<NB, 256, 0, stream>>>(ebuf, boff, deg, N);
  k_scan1<<<nch, 256, 0, stream>>>(deg, rp, csum, N);
  k_scan2<<<1, 128, 0, stream>>>(csum, nch);
  k_bfill<<<NB, 256, 0, stream>>>(ebuf, boff, rp, csum, col, N, TOT);

  const int gB = cdiv(N, 128);  // mfma gemm blocks
  const int nB = cdiv(N, 4);    // node-wave blocks (4 waves/block)

  // ---- block 0 ----
  gemm_mfma<4><<<gB, 256, 0, stream>>>(x, Wt16, asr0, adt0, feat, asb, adb, N);
  k_agg<4, 0><<<nB, 256, 0, stream>>>(feat, asb, adb, rp, col, b0, g0, be0, p0, x, hA, N);
  // ---- block 1 ----
  gemm_mfma<4><<<gB, 256, 0, stream>>>(hA, Wt16 + 16384, asr1, adt1, feat, asb, adb, N);
  k_agg<4, 0><<<nB, 256, 0, stream>>>(feat, asb, adb, rp, col, b1, g1, be1, p1, hA, hB, N);
  // ---- block 2 ----
  gemm_mfma<1><<<gB, 256, 0, stream>>>(hB, Wt16 + 32768, asr2, adt2, feat, asb, adb, N);
  k_agg<1, 1><<<nB, 256, 0, stream>>>(feat, asb, adb, rp, col, b2, nullptr, nullptr,
                                      nullptr, hB, (float*)d_out, N);
}

// Round 6
// 562.031 us; speedup vs baseline: 1.0661x; 1.0661x over previous
//
#include <hip/hip_runtime.h>

#define DEV __device__ __forceinline__

constexpr int FDIM = 128;
constexpr float LRELU_S = 0.2f;

typedef _Float16 half_t;
typedef _Float16 f16x2 __attribute__((ext_vector_type(2)));
typedef _Float16 f16x4 __attribute__((ext_vector_type(4)));
typedef _Float16 f16x8 __attribute__((ext_vector_type(8)));
typedef float    f32x4 __attribute__((ext_vector_type(4)));

DEV float lrelu(float x){ return x >= 0.f ? x : LRELU_S * x; }
// reduction across a 32-lane half (lanes stay within their half for off<=16)
DEV float hsum32(float v){
#pragma unroll
  for (int off = 16; off > 0; off >>= 1) v += __shfl_xor(v, off, 64);
  return v;
}

// ================= k_prep: transpose W0/1/2 -> fp16 [n][k], zero bcnt ========
__global__ __launch_bounds__(256)
void k_prep(const float* __restrict__ W0, const float* __restrict__ W1,
            const float* __restrict__ W2, half_t* __restrict__ Wt,
            int* __restrict__ bcnt, int nb){
  int b = blockIdx.x, t = threadIdx.x;
  if (b < 48){
    int which = b >> 4, rep = b & 15;
    const float* W = which == 0 ? W0 : (which == 1 ? W1 : W2);
    int e = rep * 1024 + t * 4;
    int k = e >> 7, n0 = e & 127;
    float4 wv = *(const float4*)(W + e);
    half_t* dst = Wt + which * 16384;
    dst[(n0 + 0) * 128 + k] = (half_t)wv.x;
    dst[(n0 + 1) * 128 + k] = (half_t)wv.y;
    dst[(n0 + 2) * 128 + k] = (half_t)wv.z;
    dst[(n0 + 3) * 128 + k] = (half_t)wv.w;
  } else {
    int i = (b - 48) * 256 + t;
    if (i < nb) bcnt[i] = 0;
  }
}

// ================= CSR build: LDS-bucketed counting sort =================
__global__ __launch_bounds__(256)
void k_bp1(const int* __restrict__ dst, int* __restrict__ bcnt, int e, int chunk){
  __shared__ int hist[1024];
  int t = threadIdx.x;
  int lo = blockIdx.x * chunk, hi = min(e, lo + chunk);
  for (int i = t; i < 1024; i += 256) hist[i] = 0;
  __syncthreads();
  for (int j = lo + t; j < hi; j += 256) atomicAdd(&hist[dst[j] >> 7], 1);
  __syncthreads();
  for (int i = t; i < 1024; i += 256){
    int c = hist[i];
    if (c) atomicAdd(&bcnt[i], c);
  }
}

__global__ __launch_bounds__(256)
void k_bscan(const int* __restrict__ bcnt, int* __restrict__ boff,
             int* __restrict__ bcur, int nb, int e){
  __shared__ int sd[256];
  int t = threadIdx.x;
  int i0 = t * 4;
  int v[4]; int tot = 0;
#pragma unroll
  for (int j = 0; j < 4; ++j){
    v[j] = (i0 + j < nb) ? bcnt[i0 + j] : 0;
    tot += v[j];
  }
  sd[t] = tot;
  __syncthreads();
  for (int off = 1; off < 256; off <<= 1){
    int o = (t >= off) ? sd[t - off] : 0;
    __syncthreads();
    sd[t] += o;
    __syncthreads();
  }
  int run = sd[t] - tot;
#pragma unroll
  for (int j = 0; j < 4; ++j){
    if (i0 + j < nb){ boff[i0 + j] = run; bcur[i0 + j] = run; }
    run += v[j];
  }
  if (t == 0) boff[nb] = e;
}

// pack edge as (src<<7)|(dst&127): bucket known from position, src<2^17.
__global__ __launch_bounds__(256)
void k_bp2(const int* __restrict__ src, const int* __restrict__ dst,
           int* __restrict__ bcur, int* __restrict__ ebuf, int e, int chunk){
  __shared__ int hist[1024];
  __shared__ int base[1024];
  int t = threadIdx.x;
  int lo = blockIdx.x * chunk, hi = min(e, lo + chunk);
  for (int i = t; i < 1024; i += 256) hist[i] = 0;
  __syncthreads();
  for (int j = lo + t; j < hi; j += 256) atomicAdd(&hist[dst[j] >> 7], 1);
  __syncthreads();
  for (int i = t; i < 1024; i += 256){
    int c = hist[i];
    base[i] = c ? atomicAdd(&bcur[i], c) : 0;
    hist[i] = 0;
  }
  __syncthreads();
  for (int j = lo + t; j < hi; j += 256){
    int d = dst[j];
    int b = d >> 7;
    int r = atomicAdd(&hist[b], 1);
    ebuf[base[b] + r] = (src[j] << 7) | (d & 127);
  }
}

__global__ __launch_bounds__(256)
void k_bdeg(const int* __restrict__ ebuf, const int* __restrict__ boff,
            int* __restrict__ deg, int n){
  __shared__ int cnt[128];
  int b = blockIdx.x, t = threadIdx.x;
  if (t < 128) cnt[t] = 1;   // self-loop
  __syncthreads();
  int lo = boff[b], hi = boff[b + 1];
  for (int j = lo + t; j < hi; j += 256) atomicAdd(&cnt[ebuf[j] & 127], 1);
  __syncthreads();
  int node = b * 128 + t;
  if (t < 128 && node < n) deg[node] = cnt[t];
}

__global__ void k_scan1(const int* __restrict__ deg, int* __restrict__ rp,
                        int* __restrict__ csum, int n){
  __shared__ int sd[256];
  int t = threadIdx.x, b = blockIdx.x;
  int base = b * 1024 + t * 4;
  int v0 = (base     < n) ? deg[base]     : 0;
  int v1 = (base + 1 < n) ? deg[base + 1] : 0;
  int v2 = (base + 2 < n) ? deg[base + 2] : 0;
  int v3 = (base + 3 < n) ? deg[base + 3] : 0;
  int tot = v0 + v1 + v2 + v3;
  sd[t] = tot;
  __syncthreads();
  for (int off = 1; off < 256; off <<= 1){
    int o = (t >= off) ? sd[t - off] : 0;
    __syncthreads();
    sd[t] += o;
    __syncthreads();
  }
  int excl = sd[t] - tot;
  if (base     < n) rp[base]     = excl;
  if (base + 1 < n) rp[base + 1] = excl + v0;
  if (base + 2 < n) rp[base + 2] = excl + v0 + v1;
  if (base + 3 < n) rp[base + 3] = excl + v0 + v1 + v2;
  if (t == 255) csum[b] = sd[255];
}
__global__ void k_scan2(int* __restrict__ csum, int nch){
  __shared__ int sd[128];
  int t = threadIdx.x;
  int my = (t < nch) ? csum[t] : 0;
  sd[t] = my;
  __syncthreads();
  for (int off = 1; off < 128; off <<= 1){
    int o = (t >= off) ? sd[t - off] : 0;
    __syncthreads();
    sd[t] += o;
    __syncthreads();
  }
  if (t < nch) csum[t] = sd[t] - my;
}

// fill col; also finalizes rp (adds csum chunk offsets) so scan3 is fused here.
__global__ __launch_bounds__(256)
void k_bfill(const int* __restrict__ ebuf, const int* __restrict__ boff,
             int* __restrict__ rp, const int* __restrict__ csum,
             int* __restrict__ col, int n, int tot){
  __shared__ int cur2[128];
  int b = blockIdx.x, t = threadIdx.x;
  int node = b * 128 + t;
  if (t < 128 && node < n){
    int r0 = rp[node] + csum[node >> 10];
    rp[node] = r0;
    col[r0] = node;          // self-loop first
    cur2[t] = r0 + 1;
  }
  if (b == 0 && t == 0) rp[n] = tot;
  __syncthreads();
  int lo = boff[b], hi = boff[b + 1];
  for (int j = lo + t; j < hi; j += 256){
    int v = ebuf[j];
    int pos = atomicAdd(&cur2[v & 127], 1);
    col[pos] = v >> 7;
  }
}

// ====== MFMA GEMM: feat[M,128](fp16) = A[M,128](fp32) @ Wt16[n][k](fp16)
// ====== + fused attention scores asb/adb
template<int HEADS>
__global__ __launch_bounds__(256)
void gemm_mfma(const float* __restrict__ A, const half_t* __restrict__ Wt16,
               const float* __restrict__ att_s, const float* __restrict__ att_d,
               half_t* __restrict__ feat, float* __restrict__ asb,
               float* __restrict__ adb, int M){
  __shared__ __align__(16) unsigned char lds[53248];
  half_t* Ah = (half_t*)lds;              // [128][72] halfs, K-chunk of 64
  half_t* Wt = (half_t*)(lds + 18432);    // [n=128][k=128] stride 136
  float*  tr = (float*)lds;               // epilogue: [4][32][68] f32

  int tid = threadIdx.x;
  int row0 = blockIdx.x * 128;
  int wid = tid >> 6, l = tid & 63;
  int wr = wid >> 1, wc = wid & 1;
  int lr = l & 15, lk = (l >> 4) * 8;

  {
    const f16x8* gW = (const f16x8*)Wt16;
#pragma unroll
    for (int rep = 0; rep < 8; ++rep){
      int c = rep * 256 + tid;
      *(f16x8*)&Wt[(c >> 4) * 136 + (c & 15) * 8] = gW[c];
    }
  }

  f32x4 acc[4][4];
#pragma unroll
  for (int mt = 0; mt < 4; ++mt)
#pragma unroll
    for (int nt = 0; nt < 4; ++nt)
      acc[mt][nt] = (f32x4){0.f, 0.f, 0.f, 0.f};

  for (int kc = 0; kc < 2; ++kc){
    __syncthreads();
    for (int rep = 0; rep < 8; ++rep){
      int e = rep * 1024 + tid * 4;
      int r = e >> 6, c = e & 63;
      int gr = row0 + r;
      float4 av = make_float4(0.f, 0.f, 0.f, 0.f);
      if (gr < M) av = *(const float4*)(A + (long long)gr * FDIM + kc * 64 + c);
      f16x4 h4 = {(half_t)av.x, (half_t)av.y, (half_t)av.z, (half_t)av.w};
      *(f16x4*)&Ah[r * 72 + c] = h4;
    }
    __syncthreads();
#pragma unroll
    for (int ksl = 0; ksl < 2; ++ksl){
      f16x8 af[4], bf[4];
      int klds = ksl * 32 + lk;
      int kw   = kc * 64 + ksl * 32 + lk;
#pragma unroll
      for (int mt = 0; mt < 4; ++mt)
        af[mt] = *(const f16x8*)&Ah[(wr * 64 + mt * 16 + lr) * 72 + klds];
#pragma unroll
      for (int nt = 0; nt < 4; ++nt)
        bf[nt] = *(const f16x8*)&Wt[(wc * 64 + nt * 16 + lr) * 136 + kw];
#pragma unroll
      for (int mt = 0; mt < 4; ++mt)
#pragma unroll
        for (int nt = 0; nt < 4; ++nt)
          acc[mt][nt] = __builtin_amdgcn_mfma_f32_16x16x32_f16(af[mt], bf[nt],
                                                               acc[mt][nt], 0, 0, 0);
    }
  }

  const int q  = tid & 3;
  const int ri = tid >> 2;
  for (int p = 0; p < 2; ++p){
    __syncthreads();
#pragma unroll
    for (int mtl = 0; mtl < 2; ++mtl){
      int mt = p * 2 + mtl;
#pragma unroll
      for (int j = 0; j < 4; ++j){
        int rowl = mtl * 16 + (l >> 4) * 4 + j;
        float* dstp = tr + (wid * 32 + rowl) * 68 + lr;
#pragma unroll
        for (int nt = 0; nt < 4; ++nt)
          dstp[nt * 16] = acc[mt][nt][j];
      }
    }
    __syncthreads();
    int br = (ri >> 5) * 64 + p * 32 + (ri & 31);
    int gr = row0 + br;
    const float* srcp = tr + (((ri >> 5) * 2 + (q >> 1)) * 32 + (ri & 31)) * 68
                          + (q & 1) * 32;
    float vals[32];
#pragma unroll
    for (int u = 0; u < 8; ++u){
      float4 v = *(const float4*)&srcp[u * 4];
      vals[u*4+0] = v.x; vals[u*4+1] = v.y; vals[u*4+2] = v.z; vals[u*4+3] = v.w;
    }
    float sc_s = 0.f, sc_d = 0.f;
#pragma unroll
    for (int cc = 0; cc < 32; ++cc){
      sc_s = fmaf(vals[cc], att_s[q * 32 + cc], sc_s);
      sc_d = fmaf(vals[cc], att_d[q * 32 + cc], sc_d);
    }
    if (HEADS == 4){
      if (gr < M){ asb[gr * 4 + q] = sc_s; adb[gr * 4 + q] = sc_d; }
    } else {
      sc_s += __shfl_xor(sc_s, 1, 64); sc_s += __shfl_xor(sc_s, 2, 64);
      sc_d += __shfl_xor(sc_d, 1, 64); sc_d += __shfl_xor(sc_d, 2, 64);
      if (q == 0 && gr < M){ asb[gr] = sc_s; adb[gr] = sc_d; }
    }
    if (gr < M){
#pragma unroll
      for (int u = 0; u < 4; ++u){
        f16x8 h8 = {(half_t)vals[u*8+0], (half_t)vals[u*8+1], (half_t)vals[u*8+2],
                    (half_t)vals[u*8+3], (half_t)vals[u*8+4], (half_t)vals[u*8+5],
                    (half_t)vals[u*8+6], (half_t)vals[u*8+7]};
        *(f16x8*)&feat[(long long)gr * FDIM + q * 32 + u * 8] = h8;
      }
    }
  }
}

// ------- aggregation + epilogue: TWO nodes per wave (32 lanes each) -------
// lane covers 4 channels (f16x4); each half-wave scans its own node's edges.
template<int HEADS, int MODE>
__global__ __launch_bounds__(256)
void k_agg(const half_t* __restrict__ feat, const float* __restrict__ asb,
           const float* __restrict__ adb, const int* __restrict__ rp,
           const int* __restrict__ col, const float* __restrict__ bias,
           const float* __restrict__ gamma, const float* __restrict__ beta,
           const float* __restrict__ prw, const float* __restrict__ resid,
           float* __restrict__ out, int n){
  __shared__ float wbuf[4][64 * HEADS];
  __shared__ int   sbuf[4][64];
  int wid = threadIdx.x >> 6;
  int gw = (blockIdx.x * 256 + threadIdx.x) >> 6;   // global wave id
  int l = threadIdx.x & 63;
  int h2 = l >> 5;            // which node of the pair
  int lh = l & 31;            // lane within half
  int i = gw * 2 + h2;
  bool valid = i < n;
  int iv = valid ? i : (n - 1);
  int c0 = lh * 4;            // 4 channels per lane
  int hh = lh >> 3;           // head of my channel group (HEADS==4)

  int s = rp[iv], epos = rp[iv + 1];
  if (!valid) epos = s;

  float ad0 = 0.f, ad1 = 0.f, ad2 = 0.f, ad3 = 0.f;
  if (HEADS == 4){
    float4 adv = *(const float4*)&adb[iv * 4];
    ad0 = adv.x; ad1 = adv.y; ad2 = adv.z; ad3 = adv.w;
  } else {
    ad0 = adb[iv];
  }

  float den0 = 0.f, den1 = 0.f, den2 = 0.f, den3 = 0.f;
  float a0 = 0.f, a1 = 0.f, a2 = 0.f, a3 = 0.f;
  const char* fb = (const char*)feat;
  for (int base = s; base < epos; base += 32){
    int j = base + lh;
    int offb = 0;
    float w0 = 0.f, w1 = 0.f, w2 = 0.f, w3 = 0.f;
    if (j < epos){
      int sj = col[j];
      offb = sj << 8;        // byte offset of fp16 feat row (128*2B)
      if (HEADS == 4){
        float4 a4 = *(const float4*)&asb[sj * 4];
        w0 = __expf(lrelu(a4.x + ad0)); den0 += w0;
        w1 = __expf(lrelu(a4.y + ad1)); den1 += w1;
        w2 = __expf(lrelu(a4.z + ad2)); den2 += w2;
        w3 = __expf(lrelu(a4.w + ad3)); den3 += w3;
      } else {
        w0 = __expf(lrelu(asb[sj] + ad0)); den0 += w0;
      }
    }
    sbuf[wid][l] = offb;
    if (HEADS == 4)
      *(float4*)&wbuf[wid][l * 4] = make_float4(w0, w1, w2, w3);
    else
      wbuf[wid][l] = w0;
    __builtin_amdgcn_wave_barrier();
    int cnt = epos - base; if (cnt > 32) cnt = 32;
#pragma unroll 8
    for (int t = 0; t < cnt; ++t){
      int e = h2 * 32 + t;
      int off = sbuf[wid][e] + c0 * 2;
      float w = (HEADS == 4) ? wbuf[wid][e * 4 + hh] : wbuf[wid][e];
      f16x4 f = *(const f16x4*)(fb + off);
      a0 = fmaf(w, (float)f[0], a0);
      a1 = fmaf(w, (float)f[1], a1);
      a2 = fmaf(w, (float)f[2], a2);
      a3 = fmaf(w, (float)f[3], a3);
    }
    __builtin_amdgcn_wave_barrier();
  }
  // per-node reductions within the 32-lane half
  den0 = hsum32(den0);
  if (HEADS == 4){ den1 = hsum32(den1); den2 = hsum32(den2); den3 = hsum32(den3); }
  float dh = (HEADS == 1) ? den0
           : (hh < 2 ? (hh == 0 ? den0 : den1) : (hh == 2 ? den2 : den3));

  float inv = 1.f / (dh + 1e-16f);
  float4 bi = *(const float4*)&bias[c0];
  float r0 = fmaf(a0, inv, bi.x);
  float r1 = fmaf(a1, inv, bi.y);
  float r2 = fmaf(a2, inv, bi.z);
  float r3 = fmaf(a3, inv, bi.w);
  float4 rs = *(const float4*)&resid[(long long)iv * FDIM + c0];
  float4 o;
  if (MODE == 0){
    float mean = hsum32(r0 + r1 + r2 + r3) * (1.f / 128.f);
    float d0 = r0 - mean, d1 = r1 - mean, d2 = r2 - mean, d3 = r3 - mean;
    float var = hsum32(d0*d0 + d1*d1 + d2*d2 + d3*d3) * (1.f / 128.f);
    float rstd = rsqrtf(var + 1e-5f);
    float pw = prw[0];
    float4 gm = *(const float4*)&gamma[c0];
    float4 bt = *(const float4*)&beta[c0];
    float y0 = d0 * rstd * gm.x + bt.x;
    float y1 = d1 * rstd * gm.y + bt.y;
    float y2 = d2 * rstd * gm.z + bt.z;
    float y3 = d3 * rstd * gm.w + bt.w;
    y0 = (y0 >= 0.f) ? y0 : pw * y0;
    y1 = (y1 >= 0.f) ? y1 : pw * y1;
    y2 = (y2 >= 0.f) ? y2 : pw * y2;
    y3 = (y3 >= 0.f) ? y3 : pw * y3;
    o = make_float4(y0 + rs.x, y1 + rs.y, y2 + rs.z, y3 + rs.w);
  } else {
    o = make_float4(r0 + rs.x, r1 + rs.y, r2 + rs.z, r3 + rs.w);
  }
  if (valid)
    *(float4*)&out[(long long)i * FDIM + c0] = o;
}

// ---------------- launch ----------------
static inline int cdiv(int a, int b){ return (a + b - 1) / b; }

extern "C" void kernel_launch(void* const* d_in, const int* in_sizes, int n_in,
                              void* d_out, int out_size, void* d_ws, size_t ws_size,
                              hipStream_t stream){
  const float* x     = (const float*)d_in[0];
  const int*   eidx  = (const int*)d_in[1];
  const float* W0    = (const float*)d_in[2];
  const float* asr0  = (const float*)d_in[3];
  const float* adt0  = (const float*)d_in[4];
  const float* b0    = (const float*)d_in[5];
  const float* g0    = (const float*)d_in[6];
  const float* be0   = (const float*)d_in[7];
  const float* p0    = (const float*)d_in[8];
  const float* W1    = (const float*)d_in[9];
  const float* asr1  = (const float*)d_in[10];
  const float* adt1  = (const float*)d_in[11];
  const float* b1    = (const float*)d_in[12];
  const float* g1    = (const float*)d_in[13];
  const float* be1   = (const float*)d_in[14];
  const float* p1    = (const float*)d_in[15];
  const float* W2    = (const float*)d_in[16];
  const float* asr2  = (const float*)d_in[17];
  const float* adt2  = (const float*)d_in[18];
  const float* b2    = (const float*)d_in[19];

  const int N = in_sizes[0] / FDIM;     // 100000
  const int E = in_sizes[1] / 2;        // 1600000
  const int TOT = E + N;
  const int NB = (N + 127) >> 7;        // buckets of 128 nodes (<=1024)

  char* p = (char*)d_ws;
  auto alloc = [&](size_t bytes) -> void* {
    void* r = (void*)p;
    p += (bytes + 255) & ~(size_t)255;
    return r;
  };
  int*    deg  = (int*)   alloc((size_t)N * 4);
  int*    rp   = (int*)   alloc((size_t)(N + 1) * 4);
  int*    csum = (int*)   alloc(128 * 4);
  int*    bcnt = (int*)   alloc(1024 * 4);
  int*    boff = (int*)   alloc(1025 * 4);
  int*    bcur = (int*)   alloc(1024 * 4);
  int*    ebuf = (int*)   alloc((size_t)E * 4);
  int*    col  = (int*)   alloc((size_t)TOT * 4);
  half_t* feat = (half_t*)alloc((size_t)N * FDIM * 2);
  half_t* Wt16 = (half_t*)alloc(3 * 16384 * 2);
  float*  asb  = (float*) alloc((size_t)N * 4 * 4);
  float*  adb  = (float*) alloc((size_t)N * 4 * 4);
  float*  hA   = (float*) alloc((size_t)N * FDIM * 4);
  float*  hB   = (float*) alloc((size_t)N * FDIM * 4);
  (void)ws_size; (void)n_in; (void)out_size;

  const int nch = cdiv(N, 1024);
  const int SBLK = 256;
  const int chunk = cdiv(E, SBLK);

  // ---- prep (W transpose + bcnt zero) and CSR build ----
  k_prep<<<48 + cdiv(NB, 256), 256, 0, stream>>>(W0, W1, W2, Wt16, bcnt, NB);
  k_bp1<<<SBLK, 256, 0, stream>>>(eidx + E, bcnt, E, chunk);
  k_bscan<<<1, 256, 0, stream>>>(bcnt, boff, bcur, NB, E);
  k_bp2<<<SBLK, 256, 0, stream>>>(eidx, eidx + E, bcur, ebuf, E, chunk);
  k_bdeg<<<NB, 256, 0, stream>>>(ebuf, boff, deg, N);
  k_scan1<<<nch, 256, 0, stream>>>(deg, rp, csum, N);
  k_scan2<<<1, 128, 0, stream>>>(csum, nch);
  k_bfill<<<NB, 256, 0, stream>>>(ebuf, boff, rp, csum, col, N, TOT);

  const int gB = cdiv(N, 128);  // mfma gemm blocks
  const int nB = cdiv(N, 8);    // 2 nodes/wave * 4 waves = 8 nodes/block

  // ---- block 0 ----
  gemm_mfma<4><<<gB, 256, 0, stream>>>(x, Wt16, asr0, adt0, feat, asb, adb, N);
  k_agg<4, 0><<<nB, 256, 0, stream>>>(feat, asb, adb, rp, col, b0, g0, be0, p0, x, hA, N);
  // ---- block 1 ----
  gemm_mfma<4><<<gB, 256, 0, stream>>>(hA, Wt16 + 16384, asr1, adt1, feat, asb, adb, N);
  k_agg<4, 0><<<nB, 256, 0, stream>>>(feat, asb, adb, rp, col, b1, g1, be1, p1, hA, hB, N);
  // ---- block 2 ----
  gemm_mfma<1><<<gB, 256, 0, stream>>>(hB, Wt16 + 32768, asr2, adt2, feat, asb, adb, N);
  k_agg<1, 1><<<nB, 256, 0, stream>>>(feat, asb, adb, rp, col, b2, nullptr, nullptr,
                                      nullptr, hB, (float*)d_out, N);
}